// Round 4
// baseline (1051.447 us; speedup 1.0000x reference)
//
#include <hip/hip_runtime.h>
#include <cstddef>

// K-Planes field eval: 4 scales x 3 planes bilinear sample (32ch), 3-way
// product per scale -> 128 feats -> MLP 128->64->64->1 (ReLU, bias-free).
//
// R4 strategy (on top of R3's bf16 [H,W,C] ws + 512thr/64pt blocks):
//  - phase0: per (pt,sample) coords computed ONCE, stored in LDS
//      (kills 8x duplicated coord math across the 8 gather threads/pt)
//  - MLP inner loops use v_pk_fma_f32 (packed dual f32 FMA, inline asm):
//      activations via ds_read_b64 (stride 130 -> aligned, conflict-free),
//      weights via s_load (wave-uniform g), op_sel broadcasts lo/hi half.

typedef unsigned short ushort_t;
typedef unsigned int uint_t;
typedef __attribute__((ext_vector_type(2))) float f32x2;

struct KParams {
  const float* x;
  const void* g[12];
  const float* w0;
  const float* w1;
  const float* w2;
  float* out;
  int N;
};

__device__ __forceinline__ ushort_t f32_to_bf16_rne(float f) {
  uint_t u = __float_as_uint(f);
  u = (u + 0x7FFFu + ((u >> 16) & 1u)) >> 16;
  return (ushort_t)u;
}

// in: [32][RR] f32  ->  out: [RR][32] bf16
__global__ __launch_bounds__(256) void transpose_chw_hwc_bf16(
    const float* __restrict__ in, ushort_t* __restrict__ out, int RR) {
  __shared__ float tile[32][65];
  const int p0 = blockIdx.x * 64;
  {
    const int tp = threadIdx.x & 63;
    const int tc = threadIdx.x >> 6;
#pragma unroll
    for (int cc = 0; cc < 8; ++cc) {
      const int c = cc * 4 + tc;
      tile[c][tp] = in[(size_t)c * RR + p0 + tp];
    }
  }
  __syncthreads();
  {
    const int c2 = threadIdx.x & 15;   // channel pair
    const int tq = threadIdx.x >> 4;   // 0..15
    uint_t* o32 = (uint_t*)out;
#pragma unroll
    for (int pp = 0; pp < 4; ++pp) {
      const int pos = pp * 16 + tq;
      const uint_t lo = f32_to_bf16_rne(tile[2 * c2 + 0][pos]);
      const uint_t hi = f32_to_bf16_rne(tile[2 * c2 + 1][pos]);
      o32[(size_t)(p0 + pos) * 16 + c2] = lo | (hi << 16);
    }
  }
}

// acc(2xf32) += broadcast(f2.lo) * w(sgpr pair)
__device__ __forceinline__ void pk_fma_lo(f32x2& acc, f32x2 f2, unsigned long w) {
  asm("v_pk_fma_f32 %0, %1, %2, %0 op_sel:[0,0,0] op_sel_hi:[0,1,1]"
      : "+v"(acc) : "v"(f2), "s"(w));
}
// acc(2xf32) += broadcast(f2.hi) * w(sgpr pair)
__device__ __forceinline__ void pk_fma_hi(f32x2& acc, f32x2 f2, unsigned long w) {
  asm("v_pk_fma_f32 %0, %1, %2, %0 op_sel:[1,0,0] op_sel_hi:[1,1,1]"
      : "+v"(acc) : "v"(f2), "s"(w));
}

template <bool CHLAST>
__global__ __launch_bounds__(512, 8) void kplanes_fused(KParams P) {
  __shared__ float fl[64][130];  // coords -> feats -> relu(h0) -> o-parts
  float* flf = &fl[0][0];
  const int t = threadIdx.x;
  const int blk0 = blockIdx.x * 64;

  // ---------------- phase 0: coords once per (pt, sample) ------------------
  // slot layout per (pt,sm): [off00,off01,off10,off11, wx,wy, RR, pad]
  // base = pt*100 + sm*8  (stride 100 -> b128 reads spread across banks)
  for (int task = t; task < 768; task += 512) {
    const int pt = task / 12;
    const int sm = task - pt * 12;
    const int s = sm / 3;
    const int pl = sm - s * 3;
    int Pi = blk0 + pt;
    if (Pi >= P.N) Pi = P.N - 1;
    const float c0 = P.x[3 * Pi + 0];
    const float c1 = P.x[3 * Pi + 1];
    const float c2 = P.x[3 * Pi + 2];
    const float cx = (pl == 2) ? c1 : c0;
    const float cy = (pl == 0) ? c1 : c2;
    const int R = 128 << s;
    const float Rm1 = (float)(R - 1);
    const float u = fminf(fmaxf((cx + 1.0f) * 0.5f * Rm1, 0.0f), Rm1);
    const float v = fminf(fmaxf((cy + 1.0f) * 0.5f * Rm1, 0.0f), Rm1);
    const float fx0 = floorf(u), fy0 = floorf(v);
    const int x0 = (int)fx0, y0 = (int)fy0;
    const int x1 = min(x0 + 1, R - 1), y1 = min(y0 + 1, R - 1);
    float* cb = flf + pt * 100 + sm * 8;
    float4 o4;
    o4.x = __int_as_float(y0 * R + x0);
    o4.y = __int_as_float(y0 * R + x1);
    o4.z = __int_as_float(y1 * R + x0);
    o4.w = __int_as_float(y1 * R + x1);
    *(float4*)cb = o4;
    cb[4] = u - fx0;
    cb[5] = v - fy0;
    cb[6] = __int_as_float(R * R);
  }
  __syncthreads();

  // ---------------- gather: feat[s][c] for channels sub*4+c ----------------
  const int pg = t >> 3;
  const int sub = t & 7;

  float feat[4][4];
#pragma unroll
  for (int s = 0; s < 4; ++s)
#pragma unroll
    for (int c = 0; c < 4; ++c) feat[s][c] = 1.0f;

#pragma unroll
  for (int s = 0; s < 4; ++s) {
#pragma unroll
    for (int pl = 0; pl < 3; ++pl) {
      const int sl = s * 3 + pl;
      const float* cb = flf + pg * 100 + sl * 8;
      const float4 o4 = *(const float4*)cb;   // broadcast across 8 subs
      const float wx = cb[4], wy = cb[5];
      const int off00 = __float_as_int(o4.x);
      const int off01 = __float_as_int(o4.y);
      const int off10 = __float_as_int(o4.z);
      const int off11 = __float_as_int(o4.w);
      const float w11 = wx * wy;
      const float w10 = wy - w11;
      const float w01 = wx - w11;
      const float w00 = 1.0f - wx - w10;

      if (CHLAST) {
        const ushort_t* gp = (const ushort_t*)P.g[sl];
        const uint2 qa = *(const uint2*)(gp + (size_t)off00 * 32 + sub * 4);
        const uint2 qb = *(const uint2*)(gp + (size_t)off01 * 32 + sub * 4);
        const uint2 qc = *(const uint2*)(gp + (size_t)off10 * 32 + sub * 4);
        const uint2 qd = *(const uint2*)(gp + (size_t)off11 * 32 + sub * 4);
        float r;
        r = __uint_as_float(qd.x << 16) * w11;
        r = fmaf(__uint_as_float(qc.x << 16), w10, r);
        r = fmaf(__uint_as_float(qb.x << 16), w01, r);
        r = fmaf(__uint_as_float(qa.x << 16), w00, r);
        feat[s][0] *= r;
        r = __uint_as_float(qd.x & 0xFFFF0000u) * w11;
        r = fmaf(__uint_as_float(qc.x & 0xFFFF0000u), w10, r);
        r = fmaf(__uint_as_float(qb.x & 0xFFFF0000u), w01, r);
        r = fmaf(__uint_as_float(qa.x & 0xFFFF0000u), w00, r);
        feat[s][1] *= r;
        r = __uint_as_float(qd.y << 16) * w11;
        r = fmaf(__uint_as_float(qc.y << 16), w10, r);
        r = fmaf(__uint_as_float(qb.y << 16), w01, r);
        r = fmaf(__uint_as_float(qa.y << 16), w00, r);
        feat[s][2] *= r;
        r = __uint_as_float(qd.y & 0xFFFF0000u) * w11;
        r = fmaf(__uint_as_float(qc.y & 0xFFFF0000u), w10, r);
        r = fmaf(__uint_as_float(qb.y & 0xFFFF0000u), w01, r);
        r = fmaf(__uint_as_float(qa.y & 0xFFFF0000u), w00, r);
        feat[s][3] *= r;
      } else {
        const float* gp = (const float*)P.g[sl];
        const int RR = __float_as_int(cb[6]);
#pragma unroll
        for (int c = 0; c < 4; ++c) {
          const size_t cbase = (size_t)(sub * 4 + c) * RR;
          const float r = gp[cbase + off00] * w00 + gp[cbase + off01] * w01 +
                          gp[cbase + off10] * w10 + gp[cbase + off11] * w11;
          feat[s][c] *= r;
        }
      }
    }
  }
  __syncthreads();  // coords fully consumed

  // publish feats (b64 pairs): fl[pg][s*32 + sub*4 + {0,2}]
#pragma unroll
  for (int s = 0; s < 4; ++s) {
    f32x2 v01, v23;
    v01[0] = feat[s][0]; v01[1] = feat[s][1];
    v23[0] = feat[s][2]; v23[1] = feat[s][3];
    *(f32x2*)&fl[pg][s * 32 + sub * 4 + 0] = v01;
    *(f32x2*)&fl[pg][s * 32 + sub * 4 + 2] = v23;
  }
  __syncthreads();

  // ---------------- MLP: thread (g,p) does j in [g*8, g*8+8) --------------
  const int p = t & 63;
  const int g = __builtin_amdgcn_readfirstlane(t >> 6);  // wave-uniform 0..7
  const float* flp = fl[p];

  // layer 0: h0 pair j: sum_k feat[k] * w0[k][g*8+2j..2j+1]
  const unsigned long* w0q = (const unsigned long*)P.w0;  // row stride 32 qw
  f32x2 acc0[4];
#pragma unroll
  for (int j = 0; j < 4; ++j) { acc0[j][0] = 0.0f; acc0[j][1] = 0.0f; }
#pragma unroll 4
  for (int k = 0; k < 128; k += 2) {
    const f32x2 f2 = *(const f32x2*)(flp + k);  // ds_read_b64
#pragma unroll
    for (int j = 0; j < 4; ++j) {
      pk_fma_lo(acc0[j], f2, w0q[(size_t)k * 32 + g * 4 + j]);
      pk_fma_hi(acc0[j], f2, w0q[(size_t)(k + 1) * 32 + g * 4 + j]);
    }
  }
  __syncthreads();  // feats fully consumed

  // relu(h0) -> fl[p][0..63]
#pragma unroll
  for (int j = 0; j < 4; ++j) {
    f32x2 v = acc0[j];
    v[0] = fmaxf(v[0], 0.0f);
    v[1] = fmaxf(v[1], 0.0f);
    *(f32x2*)&fl[p][g * 8 + 2 * j] = v;
  }
  __syncthreads();

  // layer 1
  const unsigned long* w1q = (const unsigned long*)P.w1;
  f32x2 acc1[4];
#pragma unroll
  for (int j = 0; j < 4; ++j) { acc1[j][0] = 0.0f; acc1[j][1] = 0.0f; }
#pragma unroll 4
  for (int k = 0; k < 64; k += 2) {
    const f32x2 f2 = *(const f32x2*)(flp + k);
#pragma unroll
    for (int j = 0; j < 4; ++j) {
      pk_fma_lo(acc1[j], f2, w1q[(size_t)k * 32 + g * 4 + j]);
      pk_fma_hi(acc1[j], f2, w1q[(size_t)(k + 1) * 32 + g * 4 + j]);
    }
  }

  // output partial: sum relu(h1) * w2
  const float* w2c = P.w2 + g * 8;
  float o = 0.0f;
#pragma unroll
  for (int j = 0; j < 4; ++j) {
    o = fmaf(fmaxf(acc1[j][0], 0.0f), w2c[2 * j + 0], o);
    o = fmaf(fmaxf(acc1[j][1], 0.0f), w2c[2 * j + 1], o);
  }

  __syncthreads();  // h0 region fully consumed
  ((float*)fl)[g * 64 + p] = o;
  __syncthreads();

  if (t < 64) {
    const int Po = blk0 + t;
    if (Po < P.N) {
      const float* f0 = (const float*)fl;
      float r = 0.0f;
#pragma unroll
      for (int j = 0; j < 8; ++j) r += f0[j * 64 + t];
      P.out[Po] = r;
    }
  }
}

extern "C" void kernel_launch(void* const* d_in, const int* in_sizes, int n_in,
                              void* d_out, int out_size, void* d_ws, size_t ws_size,
                              hipStream_t stream) {
  KParams P;
  P.x = (const float*)d_in[0];
  P.w0 = (const float*)d_in[13];
  P.w1 = (const float*)d_in[14];
  P.w2 = (const float*)d_in[15];
  P.out = (float*)d_out;
  const int N = in_sizes[0] / 3;
  P.N = N;

  size_t need = 0;
  for (int s = 0; s < 4; ++s) {
    const size_t R = (size_t)(128 << s);
    need += 3ull * 32ull * R * R * sizeof(ushort_t);
  }

  const int nblk = (N + 63) / 64;
  if (ws_size >= need) {
    ushort_t* w = (ushort_t*)d_ws;
    size_t off = 0;
    for (int s = 0; s < 4; ++s) {
      const int R = 128 << s;
      const int RR = R * R;
      for (int pl = 0; pl < 3; ++pl) {
        const float* src = (const float*)d_in[1 + s * 3 + pl];
        transpose_chw_hwc_bf16<<<RR / 64, 256, 0, stream>>>(src, w + off, RR);
        P.g[s * 3 + pl] = w + off;
        off += (size_t)32 * RR;
      }
    }
    kplanes_fused<true><<<nblk, 512, 0, stream>>>(P);
  } else {
    for (int k = 0; k < 12; ++k) P.g[k] = (const void*)d_in[1 + k];
    kplanes_fused<false><<<nblk, 512, 0, stream>>>(P);
  }
}

// Round 5
// 764.312 us; speedup vs baseline: 1.3757x; 1.3757x over previous
//
#include <hip/hip_runtime.h>
#include <cstddef>

// K-Planes field eval: 4 scales x 3 planes bilinear sample (32ch), 3-way
// product per scale -> 128 feats -> MLP 128->64->64->1 (ReLU, bias-free).
//
// R5 strategy (revert R4's pk_fma/coord-LDS; base = R3 at 683us):
//  - grids: [C,H,W] f32 -> [H,W,C] bf16 in d_ws (as R3)
//  - gather: 512 thr = 64 pts, 8 thr/pt x 4ch, per-thread coords (as R3),
//      feats packed bf16 into LDS with XOR swizzle (T2: avoid 16-way
//      conflicts on 256B-stride A-frag reads)
//  - MLP via MFMA bf16 16x16x32: per block layer0 [64x128]@[128x64],
//      layer1 [64x64]@[64x64]; weights pre-transposed bf16 [n][k] in ws
//      (one 16B contiguous load per B-frag); layer2 dot via shfl_xor.
//  - MFMA frag maps (m89-verified): A row=lane%16, k=8*(lane/16)+j;
//      B col=lane%16, k=8*(lane/16)+j; D col=lane&15, row=4*(lane>>4)+reg.

typedef unsigned short ushort_t;
typedef unsigned int uint_t;
typedef __bf16 bf16x8 __attribute__((ext_vector_type(8)));
typedef float f32x4 __attribute__((ext_vector_type(4)));

struct KParams {
  const float* x;
  const void* g[12];
  const float* w0;
  const float* w1;
  const float* w2;
  const ushort_t* w0T;  // [64 n][128 k] bf16
  const ushort_t* w1T;  // [64 n][64 k]  bf16
  float* out;
  int N;
};

__device__ __forceinline__ ushort_t f32_to_bf16_rne(float f) {
  uint_t u = __float_as_uint(f);
  u = (u + 0x7FFFu + ((u >> 16) & 1u)) >> 16;
  return (ushort_t)u;
}

// in: [32][RR] f32  ->  out: [RR][32] bf16
__global__ __launch_bounds__(256) void transpose_chw_hwc_bf16(
    const float* __restrict__ in, ushort_t* __restrict__ out, int RR) {
  __shared__ float tile[32][65];
  const int p0 = blockIdx.x * 64;
  {
    const int tp = threadIdx.x & 63;
    const int tc = threadIdx.x >> 6;
#pragma unroll
    for (int cc = 0; cc < 8; ++cc) {
      const int c = cc * 4 + tc;
      tile[c][tp] = in[(size_t)c * RR + p0 + tp];
    }
  }
  __syncthreads();
  {
    const int c2 = threadIdx.x & 15;
    const int tq = threadIdx.x >> 4;
    uint_t* o32 = (uint_t*)out;
#pragma unroll
    for (int pp = 0; pp < 4; ++pp) {
      const int pos = pp * 16 + tq;
      const uint_t lo = f32_to_bf16_rne(tile[2 * c2 + 0][pos]);
      const uint_t hi = f32_to_bf16_rne(tile[2 * c2 + 1][pos]);
      o32[(size_t)(p0 + pos) * 16 + c2] = lo | (hi << 16);
    }
  }
}

// w0 [128][64] -> w0T [64][128] bf16 ; w1 [64][64] -> w1T [64][64] bf16
__global__ __launch_bounds__(256) void prep_weights(
    const float* __restrict__ w0, const float* __restrict__ w1,
    ushort_t* __restrict__ w0T, ushort_t* __restrict__ w1T) {
  const int t = threadIdx.x;
  for (int i = t; i < 128 * 64; i += 256) {
    const int k = i >> 6, n = i & 63;
    w0T[n * 128 + k] = f32_to_bf16_rne(w0[i]);
  }
  for (int i = t; i < 64 * 64; i += 256) {
    const int k = i >> 6, n = i & 63;
    w1T[n * 64 + k] = f32_to_bf16_rne(w1[i]);
  }
}

__global__ __launch_bounds__(512, 8) void kplanes_fused_mfma(KParams P) {
  __shared__ ushort_t lds_feat[64 * 128];  // [pt][128] bf16, XOR-swizzled
  __shared__ ushort_t lds_h[64 * 64];      // [pt][64] bf16, XOR-swizzled
  __shared__ float oparts[2][64];

  const int t = threadIdx.x;
  const int blk0 = blockIdx.x * 64;

  // ---------------- gather: 8 thr/pt, channels [sub*4, sub*4+4) -----------
  const int pg = t >> 3;
  const int sub = t & 7;
  int Pi = blk0 + pg;
  if (Pi >= P.N) Pi = P.N - 1;
  const float c0 = P.x[3 * Pi + 0];
  const float c1 = P.x[3 * Pi + 1];
  const float c2 = P.x[3 * Pi + 2];

  float feat[4][4];
#pragma unroll
  for (int s = 0; s < 4; ++s)
#pragma unroll
    for (int c = 0; c < 4; ++c) feat[s][c] = 1.0f;

#pragma unroll
  for (int s = 0; s < 4; ++s) {
    const int R = 128 << s;
#pragma unroll
    for (int pl = 0; pl < 3; ++pl) {
      // PLANES = (0,1),(0,2),(1,2); cx -> W axis, cy -> H axis
      const float cx = (pl == 2) ? c1 : c0;
      const float cy = (pl == 0) ? c1 : c2;
      const float Rm1 = (float)(R - 1);
      const float u = fminf(fmaxf((cx + 1.0f) * 0.5f * Rm1, 0.0f), Rm1);
      const float v = fminf(fmaxf((cy + 1.0f) * 0.5f * Rm1, 0.0f), Rm1);
      const float fx0 = floorf(u), fy0 = floorf(v);
      const float wx = u - fx0, wy = v - fy0;
      const int x0 = (int)fx0, y0 = (int)fy0;
      const int x1 = min(x0 + 1, R - 1), y1 = min(y0 + 1, R - 1);
      const float w11 = wx * wy;
      const float w10 = wy - w11;
      const float w01 = wx - w11;
      const float w00 = 1.0f - wx - w10;

      const ushort_t* gp = (const ushort_t*)P.g[s * 3 + pl];
      const uint2 qa = *(const uint2*)(gp + (size_t)(y0 * R + x0) * 32 + sub * 4);
      const uint2 qb = *(const uint2*)(gp + (size_t)(y0 * R + x1) * 32 + sub * 4);
      const uint2 qc = *(const uint2*)(gp + (size_t)(y1 * R + x0) * 32 + sub * 4);
      const uint2 qd = *(const uint2*)(gp + (size_t)(y1 * R + x1) * 32 + sub * 4);
      float r;
      r = __uint_as_float(qd.x << 16) * w11;
      r = fmaf(__uint_as_float(qc.x << 16), w10, r);
      r = fmaf(__uint_as_float(qb.x << 16), w01, r);
      r = fmaf(__uint_as_float(qa.x << 16), w00, r);
      feat[s][0] *= r;
      r = __uint_as_float(qd.x & 0xFFFF0000u) * w11;
      r = fmaf(__uint_as_float(qc.x & 0xFFFF0000u), w10, r);
      r = fmaf(__uint_as_float(qb.x & 0xFFFF0000u), w01, r);
      r = fmaf(__uint_as_float(qa.x & 0xFFFF0000u), w00, r);
      feat[s][1] *= r;
      r = __uint_as_float(qd.y << 16) * w11;
      r = fmaf(__uint_as_float(qc.y << 16), w10, r);
      r = fmaf(__uint_as_float(qb.y << 16), w01, r);
      r = fmaf(__uint_as_float(qa.y << 16), w00, r);
      feat[s][2] *= r;
      r = __uint_as_float(qd.y & 0xFFFF0000u) * w11;
      r = fmaf(__uint_as_float(qc.y & 0xFFFF0000u), w10, r);
      r = fmaf(__uint_as_float(qb.y & 0xFFFF0000u), w01, r);
      r = fmaf(__uint_as_float(qa.y & 0xFFFF0000u), w00, r);
      feat[s][3] *= r;
    }
  }

  // pack to bf16, write swizzled: dword idx (s*16+sub*2) ^ ((pg&7)<<2)
  {
    uint_t* prow = (uint_t*)lds_feat + pg * 64;
    const int wxor = (pg & 7) << 2;
#pragma unroll
    for (int s = 0; s < 4; ++s) {
      uint_t d0, d1;
      asm("v_cvt_pk_bf16_f32 %0, %1, %2" : "=v"(d0) : "v"(feat[s][0]), "v"(feat[s][1]));
      asm("v_cvt_pk_bf16_f32 %0, %1, %2" : "=v"(d1) : "v"(feat[s][2]), "v"(feat[s][3]));
      const int idx = (s * 16 + sub * 2) ^ wxor;
      prow[idx] = d0;
      prow[idx + 1] = d1;
    }
  }
  __syncthreads();

  // ---------------- MLP via MFMA ------------------------------------------
  const int w = __builtin_amdgcn_readfirstlane(t >> 6);  // wave 0..7
  const int mt = w & 3;              // M-tile (16 pts)
  const int nt0 = (w >> 2) << 1;     // first of 2 N-tiles
  const int ln = t & 15;
  const int lq = (t >> 4) & 3;       // quarter-wave
  const int arow = mt * 16 + ln;     // A-frag row (point)

  // layer 0: [64x128] @ [128x64]
  const uint_t* farow = (const uint_t*)lds_feat + arow * 64;
  const int axor = (arow & 7) << 2;  // dword units
  f32x4 acc0a = {0.f, 0.f, 0.f, 0.f}, acc0b = {0.f, 0.f, 0.f, 0.f};
  const ushort_t* w0a = P.w0T + (nt0 * 16 + ln) * 128 + lq * 8;
  const ushort_t* w0b = w0a + 16 * 128;
#pragma unroll
  for (int kt = 0; kt < 4; ++kt) {
    const bf16x8 aF = *(const bf16x8*)(farow + ((kt * 16 + lq * 4) ^ axor));
    const bf16x8 bFa = *(const bf16x8*)(w0a + kt * 32);
    const bf16x8 bFb = *(const bf16x8*)(w0b + kt * 32);
    acc0a = __builtin_amdgcn_mfma_f32_16x16x32_bf16(aF, bFa, acc0a, 0, 0, 0);
    acc0b = __builtin_amdgcn_mfma_f32_16x16x32_bf16(aF, bFb, acc0b, 0, 0, 0);
  }

  // relu(h0) -> bf16 -> lds_h swizzled (D: row=mt*16+lq*4+j, col=nt*16+ln)
#pragma unroll
  for (int i = 0; i < 2; ++i) {
    const f32x4 a = i ? acc0b : acc0a;
    const int col = (nt0 + i) * 16 + ln;
#pragma unroll
    for (int j = 0; j < 4; ++j) {
      const float v = fmaxf(a[j], 0.0f);
      uint_t dv;
      asm("v_cvt_pk_bf16_f32 %0, %1, %2" : "=v"(dv) : "v"(v), "v"(v));
      const int r = mt * 16 + lq * 4 + j;
      lds_h[r * 64 + (col ^ ((r & 7) << 3))] = (ushort_t)dv;
    }
  }
  __syncthreads();

  // layer 1: [64x64] @ [64x64]
  const ushort_t* hrow = lds_h + arow * 64;
  const int hxor = (arow & 7) << 3;  // ushort units
  f32x4 acc1a = {0.f, 0.f, 0.f, 0.f}, acc1b = {0.f, 0.f, 0.f, 0.f};
  const ushort_t* w1a = P.w1T + (nt0 * 16 + ln) * 64 + lq * 8;
  const ushort_t* w1b = w1a + 16 * 64;
#pragma unroll
  for (int kt = 0; kt < 2; ++kt) {
    const bf16x8 aF = *(const bf16x8*)(hrow + ((kt * 32 + lq * 8) ^ hxor));
    const bf16x8 bFa = *(const bf16x8*)(w1a + kt * 32);
    const bf16x8 bFb = *(const bf16x8*)(w1b + kt * 32);
    acc1a = __builtin_amdgcn_mfma_f32_16x16x32_bf16(aF, bFa, acc1a, 0, 0, 0);
    acc1b = __builtin_amdgcn_mfma_f32_16x16x32_bf16(aF, bFb, acc1b, 0, 0, 0);
  }

  // layer 2: out[pt] = sum_col relu(h1)*w2 ; reduce across ln (16 lanes)
  const float w2a = P.w2[nt0 * 16 + ln];
  const float w2b = P.w2[(nt0 + 1) * 16 + ln];
  float part[4];
#pragma unroll
  for (int j = 0; j < 4; ++j)
    part[j] = fmaxf(acc1a[j], 0.f) * w2a + fmaxf(acc1b[j], 0.f) * w2b;
#pragma unroll
  for (int j = 0; j < 4; ++j) {
    part[j] += __shfl_xor(part[j], 1);
    part[j] += __shfl_xor(part[j], 2);
    part[j] += __shfl_xor(part[j], 4);
    part[j] += __shfl_xor(part[j], 8);
  }
  if (ln == 0) {
#pragma unroll
    for (int j = 0; j < 4; ++j)
      oparts[w >> 2][mt * 16 + lq * 4 + j] = part[j];
  }
  __syncthreads();

  if (t < 64) {
    const int Po = blk0 + t;
    if (Po < P.N) P.out[Po] = oparts[0][t] + oparts[1][t];
  }
}

// fallback (ws too small): f32 [C,H,W] grids, scalar MLP (R3 structure)
__global__ __launch_bounds__(512, 8) void kplanes_fused_scalar(KParams P) {
  __shared__ float fl[64][130];
  const int t = threadIdx.x;
  const int pg = t >> 3;
  const int sub = t & 7;
  const int blk0 = blockIdx.x * 64;

  int Pi = blk0 + pg;
  if (Pi >= P.N) Pi = P.N - 1;
  const float c0 = P.x[3 * Pi + 0];
  const float c1 = P.x[3 * Pi + 1];
  const float c2 = P.x[3 * Pi + 2];

  float feat[4][4];
#pragma unroll
  for (int s = 0; s < 4; ++s)
#pragma unroll
    for (int c = 0; c < 4; ++c) feat[s][c] = 1.0f;

#pragma unroll
  for (int s = 0; s < 4; ++s) {
    const int R = 128 << s;
    const int RR = R * R;
#pragma unroll
    for (int pl = 0; pl < 3; ++pl) {
      const float cx = (pl == 2) ? c1 : c0;
      const float cy = (pl == 0) ? c1 : c2;
      const float Rm1 = (float)(R - 1);
      const float u = fminf(fmaxf((cx + 1.0f) * 0.5f * Rm1, 0.0f), Rm1);
      const float v = fminf(fmaxf((cy + 1.0f) * 0.5f * Rm1, 0.0f), Rm1);
      const float fx0 = floorf(u), fy0 = floorf(v);
      const float wx = u - fx0, wy = v - fy0;
      const int x0 = (int)fx0, y0 = (int)fy0;
      const int x1 = min(x0 + 1, R - 1), y1 = min(y0 + 1, R - 1);
      const float w11 = wx * wy;
      const float w10 = wy - w11;
      const float w01 = wx - w11;
      const float w00 = 1.0f - wx - w10;
      const float* gp = (const float*)P.g[s * 3 + pl];
      const int i00 = y0 * R + x0, i01 = y0 * R + x1;
      const int i10 = y1 * R + x0, i11 = y1 * R + x1;
#pragma unroll
      for (int c = 0; c < 4; ++c) {
        const size_t cb = (size_t)(sub * 4 + c) * RR;
        feat[s][c] *= gp[cb + i00] * w00 + gp[cb + i01] * w01 +
                      gp[cb + i10] * w10 + gp[cb + i11] * w11;
      }
    }
  }

#pragma unroll
  for (int s = 0; s < 4; ++s)
#pragma unroll
    for (int c = 0; c < 4; ++c)
      fl[pg][s * 32 + sub * 4 + c] = feat[s][c];
  __syncthreads();

  const int p = t & 63;
  const int g = __builtin_amdgcn_readfirstlane(t >> 6);

  const float* w0c = P.w0 + g * 8;
  float part[8];
#pragma unroll
  for (int jj = 0; jj < 8; ++jj) part[jj] = 0.0f;
#pragma unroll 16
  for (int k = 0; k < 128; ++k) {
    const float f = fl[p][k];
#pragma unroll
    for (int jj = 0; jj < 8; ++jj)
      part[jj] = fmaf(f, w0c[(size_t)k * 64 + jj], part[jj]);
  }
  __syncthreads();
#pragma unroll
  for (int jj = 0; jj < 8; ++jj)
    fl[p][g * 8 + jj] = fmaxf(part[jj], 0.0f);
  __syncthreads();

  const float* w1c = P.w1 + g * 8;
  float h1[8];
#pragma unroll
  for (int jj = 0; jj < 8; ++jj) h1[jj] = 0.0f;
#pragma unroll 16
  for (int k = 0; k < 64; ++k) {
    const float a = fl[p][k];
#pragma unroll
    for (int jj = 0; jj < 8; ++jj)
      h1[jj] = fmaf(a, w1c[(size_t)k * 64 + jj], h1[jj]);
  }

  const float* w2c = P.w2 + g * 8;
  float o = 0.0f;
#pragma unroll
  for (int jj = 0; jj < 8; ++jj)
    o = fmaf(fmaxf(h1[jj], 0.0f), w2c[jj], o);

  __syncthreads();
  ((float*)fl)[g * 64 + p] = o;
  __syncthreads();

  if (t < 64) {
    const int Po = blk0 + t;
    if (Po < P.N) {
      const float* f0 = (const float*)fl;
      float r = 0.0f;
#pragma unroll
      for (int j = 0; j < 8; ++j) r += f0[j * 64 + t];
      P.out[Po] = r;
    }
  }
}

extern "C" void kernel_launch(void* const* d_in, const int* in_sizes, int n_in,
                              void* d_out, int out_size, void* d_ws, size_t ws_size,
                              hipStream_t stream) {
  KParams P;
  P.x = (const float*)d_in[0];
  P.w0 = (const float*)d_in[13];
  P.w1 = (const float*)d_in[14];
  P.w2 = (const float*)d_in[15];
  P.out = (float*)d_out;
  const int N = in_sizes[0] / 3;
  P.N = N;

  size_t need = 0;
  for (int s = 0; s < 4; ++s) {
    const size_t R = (size_t)(128 << s);
    need += 3ull * 32ull * R * R * sizeof(ushort_t);
  }
  const size_t walign = (need + 255) & ~(size_t)255;
  const size_t wbytes = (size_t)(64 * 128 + 64 * 64) * sizeof(ushort_t);

  const int nblk = (N + 63) / 64;
  if (ws_size >= walign + wbytes) {
    ushort_t* w = (ushort_t*)d_ws;
    size_t off = 0;
    for (int s = 0; s < 4; ++s) {
      const int R = 128 << s;
      const int RR = R * R;
      for (int pl = 0; pl < 3; ++pl) {
        const float* src = (const float*)d_in[1 + s * 3 + pl];
        transpose_chw_hwc_bf16<<<RR / 64, 256, 0, stream>>>(src, w + off, RR);
        P.g[s * 3 + pl] = w + off;
        off += (size_t)32 * RR;
      }
    }
    ushort_t* w0T = (ushort_t*)((char*)d_ws + walign);
    ushort_t* w1T = w0T + 64 * 128;
    P.w0T = w0T;
    P.w1T = w1T;
    prep_weights<<<1, 256, 0, stream>>>(P.w0, P.w1, w0T, w1T);
    kplanes_fused_mfma<<<nblk, 512, 0, stream>>>(P);
  } else {
    for (int k = 0; k < 12; ++k) P.g[k] = (const void*)d_in[1 + k];
    P.w0T = nullptr;
    P.w1T = nullptr;
    kplanes_fused_scalar<<<nblk, 512, 0, stream>>>(P);
  }
}

// Round 6
// 729.994 us; speedup vs baseline: 1.4403x; 1.0470x over previous
//
#include <hip/hip_runtime.h>
#include <cstddef>

// K-Planes field eval: 4 scales x 3 planes bilinear sample (32ch), 3-way
// product per scale -> 128 feats -> MLP 128->64->64->1 (ReLU, bias-free).
//
// R6 strategy (on top of R5's bf16 [H,W,C] grids + MFMA MLP):
//  - stage1: 768 (pt,sample) coord-sets computed ONCE into LDS
//  - stage2: thread (pt,q) owns (s=2j+(q>>2), chgroup=q&3), loops 3 planes
//      in-register; 4 adjacent lanes read consecutive 16B of the SAME
//      corner -> coalesced 64B; 24 dwordx4 loads/thread (was 48 dwordx2)
//  - LDS arena (40960B exact, 4 blk/CU): coords[24576] reused by h/oparts;
//      feat[16384] reused by px staging
//  - MLP via MFMA bf16 16x16x32 (unchanged from R5, hardware-validated maps)
//  - transposes merged 12 -> 4 launches (gridDim.y = 3 planes)

typedef unsigned short ushort_t;
typedef unsigned int uint_t;
typedef __bf16 bf16x8 __attribute__((ext_vector_type(8)));
typedef float f32x4 __attribute__((ext_vector_type(4)));

struct KParams {
  const float* x;
  const void* g[12];
  const float* w0;
  const float* w1;
  const float* w2;
  const ushort_t* w0T;  // [64 n][128 k] bf16
  const ushort_t* w1T;  // [64 n][64 k]  bf16
  float* out;
  int N;
};

struct TP3 {
  const float* src[3];
  ushort_t* dst[3];
  int RR;
};

__device__ __forceinline__ ushort_t f32_to_bf16_rne(float f) {
  uint_t u = __float_as_uint(f);
  u = (u + 0x7FFFu + ((u >> 16) & 1u)) >> 16;
  return (ushort_t)u;
}

// in: [32][RR] f32  ->  out: [RR][32] bf16   (3 planes per launch)
__global__ __launch_bounds__(256) void transpose3(TP3 tp) {
  const float* __restrict__ in = tp.src[blockIdx.y];
  ushort_t* __restrict__ out = tp.dst[blockIdx.y];
  const int RR = tp.RR;
  __shared__ float tile[32][65];
  const int p0 = blockIdx.x * 64;
  {
    const int tp_ = threadIdx.x & 63;
    const int tc = threadIdx.x >> 6;
#pragma unroll
    for (int cc = 0; cc < 8; ++cc) {
      const int c = cc * 4 + tc;
      tile[c][tp_] = in[(size_t)c * RR + p0 + tp_];
    }
  }
  __syncthreads();
  {
    const int c2 = threadIdx.x & 15;
    const int tq = threadIdx.x >> 4;
    uint_t* o32 = (uint_t*)out;
#pragma unroll
    for (int pp = 0; pp < 4; ++pp) {
      const int pos = pp * 16 + tq;
      const uint_t lo = f32_to_bf16_rne(tile[2 * c2 + 0][pos]);
      const uint_t hi = f32_to_bf16_rne(tile[2 * c2 + 1][pos]);
      o32[(size_t)(p0 + pos) * 16 + c2] = lo | (hi << 16);
    }
  }
}

// w0 [128][64] -> w0T [64][128] bf16 ; w1 [64][64] -> w1T [64][64] bf16
__global__ __launch_bounds__(256) void prep_weights(
    const float* __restrict__ w0, const float* __restrict__ w1,
    ushort_t* __restrict__ w0T, ushort_t* __restrict__ w1T) {
  const int t = threadIdx.x;
  for (int i = t; i < 128 * 64; i += 256) {
    const int k = i >> 6, n = i & 63;
    w0T[n * 128 + k] = f32_to_bf16_rne(w0[i]);
  }
  for (int i = t; i < 64 * 64; i += 256) {
    const int k = i >> 6, n = i & 63;
    w1T[n * 64 + k] = f32_to_bf16_rne(w1[i]);
  }
}

__global__ __launch_bounds__(512, 8) void kplanes_fused_mfma(KParams P) {
  // Arena (exactly 40960 B -> 4 blocks/CU):
  //  [0,24576)  coords: 768 sets x 8 dwords {o00,o01,o10,o11,wx,wy,-,-}
  //             reused later: lds_h [0,8192), oparts [8192,8704)
  //  [24576,40960) lds_feat [64][64] dwords (bf16 pairs), XOR-swizzled
  //             reused earlier: px staging [24576,25344)
  __shared__ float arena[10240];
  int* ci = (int*)arena;
  float* cf = arena;
  uint_t* feat32 = (uint_t*)(arena + 6144);
  float* px = arena + 6144;

  const int t = threadIdx.x;
  const int blk0 = blockIdx.x * 64;

  // ---------------- px staging: 64 pts x 3 coords -------------------------
  if (t < 192) {
    const int p = t / 3, e = t - p * 3;
    int Pi = blk0 + p;
    if (Pi >= P.N) Pi = P.N - 1;
    px[t] = P.x[3 * Pi + e];
  }
  __syncthreads();

  // ---------------- stage 1: coords once per (pt, sample) -----------------
  // task = sm*64 + pt, sm = pl*4 + s
  for (int task = t; task < 768; task += 512) {
    const int pt = task & 63;
    const int sm = task >> 6;
    const int pl = sm >> 2;
    const int s = sm & 3;
    const float cx = (pl == 2) ? px[pt * 3 + 1] : px[pt * 3 + 0];
    const float cy = (pl == 0) ? px[pt * 3 + 1] : px[pt * 3 + 2];
    const int R = 128 << s;
    const float Rm1 = (float)(R - 1);
    const float u = fminf(fmaxf((cx + 1.0f) * 0.5f * Rm1, 0.0f), Rm1);
    const float v = fminf(fmaxf((cy + 1.0f) * 0.5f * Rm1, 0.0f), Rm1);
    const float fx0 = floorf(u), fy0 = floorf(v);
    const int x0 = (int)fx0, y0 = (int)fy0;
    const int x1 = min(x0 + 1, R - 1), y1 = min(y0 + 1, R - 1);
    const int base = task * 8;
    int4 o4;
    o4.x = y0 * R + x0;
    o4.y = y0 * R + x1;
    o4.z = y1 * R + x0;
    o4.w = y1 * R + x1;
    *(int4*)(ci + base) = o4;
    cf[base + 4] = u - fx0;
    cf[base + 5] = v - fy0;
  }
  __syncthreads();

  // ---------------- stage 2: gather, 16B loads, planes in-register --------
  const int pt = t >> 3;
  const int q = t & 7;
  const int cg = q & 3;   // 8-channel group
  const int sh = q >> 2;  // scale half
  uint_t* prow = feat32 + pt * 64;
  const int wxor = (pt & 7) << 2;

#pragma unroll
  for (int j = 0; j < 2; ++j) {
    const int s = 2 * j + sh;
    float f[8];
#pragma unroll
    for (int c = 0; c < 8; ++c) f[c] = 1.0f;

#pragma unroll
    for (int pl = 0; pl < 3; ++pl) {
      const int base = ((pl * 4 + s) * 64 + pt) * 8;
      const int4 o4 = *(const int4*)(ci + base);
      const float wx = cf[base + 4], wy = cf[base + 5];
      const float w11 = wx * wy;
      const float w10 = wy - w11;
      const float w01 = wx - w11;
      const float w00 = 1.0f - wx - w10;
      const ushort_t* gp = (const ushort_t*)P.g[s * 3 + pl];
      const uint4 qa = *(const uint4*)(gp + (size_t)o4.x * 32 + cg * 8);
      const uint4 qb = *(const uint4*)(gp + (size_t)o4.y * 32 + cg * 8);
      const uint4 qc = *(const uint4*)(gp + (size_t)o4.z * 32 + cg * 8);
      const uint4 qd = *(const uint4*)(gp + (size_t)o4.w * 32 + cg * 8);
#define CH2(dA, dB, dC, dD, i0, i1)                                \
  {                                                                \
    float rl = __uint_as_float((dD) << 16) * w11;                  \
    rl = fmaf(__uint_as_float((dC) << 16), w10, rl);               \
    rl = fmaf(__uint_as_float((dB) << 16), w01, rl);               \
    rl = fmaf(__uint_as_float((dA) << 16), w00, rl);               \
    f[i0] *= rl;                                                   \
    float rh = __uint_as_float((dD)&0xFFFF0000u) * w11;            \
    rh = fmaf(__uint_as_float((dC)&0xFFFF0000u), w10, rh);         \
    rh = fmaf(__uint_as_float((dB)&0xFFFF0000u), w01, rh);         \
    rh = fmaf(__uint_as_float((dA)&0xFFFF0000u), w00, rh);         \
    f[i1] *= rh;                                                   \
  }
      CH2(qa.x, qb.x, qc.x, qd.x, 0, 1)
      CH2(qa.y, qb.y, qc.y, qd.y, 2, 3)
      CH2(qa.z, qb.z, qc.z, qd.z, 4, 5)
      CH2(qa.w, qb.w, qc.w, qd.w, 6, 7)
#undef CH2
    }

    // pack 8 feats -> 4 dwords, one swizzled b128 write
    uint_t d0, d1, d2, d3;
    asm("v_cvt_pk_bf16_f32 %0, %1, %2" : "=v"(d0) : "v"(f[0]), "v"(f[1]));
    asm("v_cvt_pk_bf16_f32 %0, %1, %2" : "=v"(d1) : "v"(f[2]), "v"(f[3]));
    asm("v_cvt_pk_bf16_f32 %0, %1, %2" : "=v"(d2) : "v"(f[4]), "v"(f[5]));
    asm("v_cvt_pk_bf16_f32 %0, %1, %2" : "=v"(d3) : "v"(f[6]), "v"(f[7]));
    uint4 dv;
    dv.x = d0; dv.y = d1; dv.z = d2; dv.w = d3;
    *(uint4*)(prow + ((s * 16 + cg * 4) ^ wxor)) = dv;
  }
  __syncthreads();

  // ---------------- MLP via MFMA (R5 structure, HW-validated maps) --------
  ushort_t* lds_h = (ushort_t*)arena;                  // [0, 8192)
  float(*oparts)[64] = (float(*)[64])(arena + 2048);   // [8192, 8704)

  const int w = __builtin_amdgcn_readfirstlane(t >> 6);  // wave 0..7
  const int mt = w & 3;
  const int nt0 = (w >> 2) << 1;
  const int ln = t & 15;
  const int lq = (t >> 4) & 3;
  const int arow = mt * 16 + ln;

  // layer 0: [64x128] @ [128x64]
  const uint_t* farow = feat32 + arow * 64;
  const int axor = (arow & 7) << 2;
  f32x4 acc0a = {0.f, 0.f, 0.f, 0.f}, acc0b = {0.f, 0.f, 0.f, 0.f};
  const ushort_t* w0a = P.w0T + (nt0 * 16 + ln) * 128 + lq * 8;
  const ushort_t* w0b = w0a + 16 * 128;
#pragma unroll
  for (int kt = 0; kt < 4; ++kt) {
    const bf16x8 aF = *(const bf16x8*)(farow + ((kt * 16 + lq * 4) ^ axor));
    const bf16x8 bFa = *(const bf16x8*)(w0a + kt * 32);
    const bf16x8 bFb = *(const bf16x8*)(w0b + kt * 32);
    acc0a = __builtin_amdgcn_mfma_f32_16x16x32_bf16(aF, bFa, acc0a, 0, 0, 0);
    acc0b = __builtin_amdgcn_mfma_f32_16x16x32_bf16(aF, bFb, acc0b, 0, 0, 0);
  }

  // relu(h0) -> bf16 -> lds_h swizzled
#pragma unroll
  for (int i = 0; i < 2; ++i) {
    const f32x4 a = i ? acc0b : acc0a;
    const int col = (nt0 + i) * 16 + ln;
#pragma unroll
    for (int jj = 0; jj < 4; ++jj) {
      const float v = fmaxf(a[jj], 0.0f);
      uint_t dv;
      asm("v_cvt_pk_bf16_f32 %0, %1, %2" : "=v"(dv) : "v"(v), "v"(v));
      const int r = mt * 16 + lq * 4 + jj;
      lds_h[r * 64 + (col ^ ((r & 7) << 3))] = (ushort_t)dv;
    }
  }
  __syncthreads();

  // layer 1: [64x64] @ [64x64]
  const ushort_t* hrow = lds_h + arow * 64;
  const int hxor = (arow & 7) << 3;
  f32x4 acc1a = {0.f, 0.f, 0.f, 0.f}, acc1b = {0.f, 0.f, 0.f, 0.f};
  const ushort_t* w1a = P.w1T + (nt0 * 16 + ln) * 64 + lq * 8;
  const ushort_t* w1b = w1a + 16 * 64;
#pragma unroll
  for (int kt = 0; kt < 2; ++kt) {
    const bf16x8 aF = *(const bf16x8*)(hrow + ((kt * 32 + lq * 8) ^ hxor));
    const bf16x8 bFa = *(const bf16x8*)(w1a + kt * 32);
    const bf16x8 bFb = *(const bf16x8*)(w1b + kt * 32);
    acc1a = __builtin_amdgcn_mfma_f32_16x16x32_bf16(aF, bFa, acc1a, 0, 0, 0);
    acc1b = __builtin_amdgcn_mfma_f32_16x16x32_bf16(aF, bFb, acc1b, 0, 0, 0);
  }

  // layer 2: dot with w2, reduce across ln
  const float w2a = P.w2[nt0 * 16 + ln];
  const float w2b = P.w2[(nt0 + 1) * 16 + ln];
  float part[4];
#pragma unroll
  for (int jj = 0; jj < 4; ++jj)
    part[jj] = fmaxf(acc1a[jj], 0.f) * w2a + fmaxf(acc1b[jj], 0.f) * w2b;
#pragma unroll
  for (int jj = 0; jj < 4; ++jj) {
    part[jj] += __shfl_xor(part[jj], 1);
    part[jj] += __shfl_xor(part[jj], 2);
    part[jj] += __shfl_xor(part[jj], 4);
    part[jj] += __shfl_xor(part[jj], 8);
  }
  if (ln == 0) {
#pragma unroll
    for (int jj = 0; jj < 4; ++jj)
      oparts[w >> 2][mt * 16 + lq * 4 + jj] = part[jj];
  }
  __syncthreads();

  if (t < 64) {
    const int Po = blk0 + t;
    if (Po < P.N) P.out[Po] = oparts[0][t] + oparts[1][t];
  }
}

// fallback (ws too small): f32 [C,H,W] grids, scalar MLP (R3 structure)
__global__ __launch_bounds__(512, 8) void kplanes_fused_scalar(KParams P) {
  __shared__ float fl[64][130];
  const int t = threadIdx.x;
  const int pg = t >> 3;
  const int sub = t & 7;
  const int blk0 = blockIdx.x * 64;

  int Pi = blk0 + pg;
  if (Pi >= P.N) Pi = P.N - 1;
  const float c0 = P.x[3 * Pi + 0];
  const float c1 = P.x[3 * Pi + 1];
  const float c2 = P.x[3 * Pi + 2];

  float feat[4][4];
#pragma unroll
  for (int s = 0; s < 4; ++s)
#pragma unroll
    for (int c = 0; c < 4; ++c) feat[s][c] = 1.0f;

#pragma unroll
  for (int s = 0; s < 4; ++s) {
    const int R = 128 << s;
    const int RR = R * R;
#pragma unroll
    for (int pl = 0; pl < 3; ++pl) {
      const float cx = (pl == 2) ? c1 : c0;
      const float cy = (pl == 0) ? c1 : c2;
      const float Rm1 = (float)(R - 1);
      const float u = fminf(fmaxf((cx + 1.0f) * 0.5f * Rm1, 0.0f), Rm1);
      const float v = fminf(fmaxf((cy + 1.0f) * 0.5f * Rm1, 0.0f), Rm1);
      const float fx0 = floorf(u), fy0 = floorf(v);
      const float wx = u - fx0, wy = v - fy0;
      const int x0 = (int)fx0, y0 = (int)fy0;
      const int x1 = min(x0 + 1, R - 1), y1 = min(y0 + 1, R - 1);
      const float w11 = wx * wy;
      const float w10 = wy - w11;
      const float w01 = wx - w11;
      const float w00 = 1.0f - wx - w10;
      const float* gp = (const float*)P.g[s * 3 + pl];
      const int i00 = y0 * R + x0, i01 = y0 * R + x1;
      const int i10 = y1 * R + x0, i11 = y1 * R + x1;
#pragma unroll
      for (int c = 0; c < 4; ++c) {
        const size_t cb = (size_t)(sub * 4 + c) * RR;
        feat[s][c] *= gp[cb + i00] * w00 + gp[cb + i01] * w01 +
                      gp[cb + i10] * w10 + gp[cb + i11] * w11;
      }
    }
  }

#pragma unroll
  for (int s = 0; s < 4; ++s)
#pragma unroll
    for (int c = 0; c < 4; ++c)
      fl[pg][s * 32 + sub * 4 + c] = feat[s][c];
  __syncthreads();

  const int p = t & 63;
  const int g = __builtin_amdgcn_readfirstlane(t >> 6);

  const float* w0c = P.w0 + g * 8;
  float part[8];
#pragma unroll
  for (int jj = 0; jj < 8; ++jj) part[jj] = 0.0f;
#pragma unroll 16
  for (int k = 0; k < 128; ++k) {
    const float f = fl[p][k];
#pragma unroll
    for (int jj = 0; jj < 8; ++jj)
      part[jj] = fmaf(f, w0c[(size_t)k * 64 + jj], part[jj]);
  }
  __syncthreads();
#pragma unroll
  for (int jj = 0; jj < 8; ++jj)
    fl[p][g * 8 + jj] = fmaxf(part[jj], 0.0f);
  __syncthreads();

  const float* w1c = P.w1 + g * 8;
  float h1[8];
#pragma unroll
  for (int jj = 0; jj < 8; ++jj) h1[jj] = 0.0f;
#pragma unroll 16
  for (int k = 0; k < 64; ++k) {
    const float a = fl[p][k];
#pragma unroll
    for (int jj = 0; jj < 8; ++jj)
      h1[jj] = fmaf(a, w1c[(size_t)k * 64 + jj], h1[jj]);
  }

  const float* w2c = P.w2 + g * 8;
  float o = 0.0f;
#pragma unroll
  for (int jj = 0; jj < 8; ++jj)
    o = fmaf(fmaxf(h1[jj], 0.0f), w2c[jj], o);

  __syncthreads();
  ((float*)fl)[g * 64 + p] = o;
  __syncthreads();

  if (t < 64) {
    const int Po = blk0 + t;
    if (Po < P.N) {
      const float* f0 = (const float*)fl;
      float r = 0.0f;
#pragma unroll
      for (int j = 0; j < 8; ++j) r += f0[j * 64 + t];
      P.out[Po] = r;
    }
  }
}

extern "C" void kernel_launch(void* const* d_in, const int* in_sizes, int n_in,
                              void* d_out, int out_size, void* d_ws, size_t ws_size,
                              hipStream_t stream) {
  KParams P;
  P.x = (const float*)d_in[0];
  P.w0 = (const float*)d_in[13];
  P.w1 = (const float*)d_in[14];
  P.w2 = (const float*)d_in[15];
  P.out = (float*)d_out;
  const int N = in_sizes[0] / 3;
  P.N = N;

  size_t need = 0;
  for (int s = 0; s < 4; ++s) {
    const size_t R = (size_t)(128 << s);
    need += 3ull * 32ull * R * R * sizeof(ushort_t);
  }
  const size_t walign = (need + 255) & ~(size_t)255;
  const size_t wbytes = (size_t)(64 * 128 + 64 * 64) * sizeof(ushort_t);

  const int nblk = (N + 63) / 64;
  if (ws_size >= walign + wbytes) {
    ushort_t* w = (ushort_t*)d_ws;
    size_t off = 0;
    for (int s = 0; s < 4; ++s) {
      const int R = 128 << s;
      const int RR = R * R;
      TP3 tp;
      tp.RR = RR;
      for (int pl = 0; pl < 3; ++pl) {
        tp.src[pl] = (const float*)d_in[1 + s * 3 + pl];
        tp.dst[pl] = w + off;
        P.g[s * 3 + pl] = w + off;
        off += (size_t)32 * RR;
      }
      dim3 grid(RR / 64, 3);
      transpose3<<<grid, 256, 0, stream>>>(tp);
    }
    ushort_t* w0T = (ushort_t*)((char*)d_ws + walign);
    ushort_t* w1T = w0T + 64 * 128;
    P.w0T = w0T;
    P.w1T = w1T;
    prep_weights<<<1, 256, 0, stream>>>(P.w0, P.w1, w0T, w1T);
    kplanes_fused_mfma<<<nblk, 512, 0, stream>>>(P);
  } else {
    for (int k = 0; k < 12; ++k) P.g[k] = (const void*)d_in[1 + k];
    P.w0T = nullptr;
    P.w1T = nullptr;
    kplanes_fused_scalar<<<nblk, 512, 0, stream>>>(P);
  }
}

// Round 7
// 656.586 us; speedup vs baseline: 1.6014x; 1.1118x over previous
//
#include <hip/hip_runtime.h>
#include <cstddef>

// K-Planes field eval: 4 scales x 3 planes bilinear sample (32ch), 3-way
// product per scale -> 128 feats -> MLP 128->64->64->1 (ReLU, bias-free).
//
// R7 strategy (R6 fused kernel kept intact; add spatial locality):
//  - Morton counting-sort of points (5 bits/axis, 32768 buckets):
//      hist (global atomics) -> 1-block scan -> scatter (sidx + x_sorted)
//      -> each 64-pt block samples a ~270 KB L2-resident grid neighborhood
//  - fused kernel reads x_sorted (coalesced), writes out[sidx[i]] (scatter)
//  - bijective XCD-chunked block swizzle (nblk%8!=0-safe) for per-XCD L2 reuse
//  - sort is value-order-independent: atomic cursor nondeterminism only
//      permutes bucket-internal order; every point's output value/slot is fixed

typedef unsigned short ushort_t;
typedef unsigned int uint_t;
typedef __bf16 bf16x8 __attribute__((ext_vector_type(8)));
typedef float f32x4 __attribute__((ext_vector_type(4)));

#define NBUCKET 32768

struct KParams {
  const float* x;
  const void* g[12];
  const float* w0;
  const float* w1;
  const float* w2;
  const ushort_t* w0T;  // [64 n][128 k] bf16
  const ushort_t* w1T;  // [64 n][64 k]  bf16
  const float* xs;      // sorted points [N][3]
  const int* sidx;      // sorted -> original index
  float* out;
  int N;
};

struct TP3 {
  const float* src[3];
  ushort_t* dst[3];
  int RR;
};

__device__ __forceinline__ ushort_t f32_to_bf16_rne(float f) {
  uint_t u = __float_as_uint(f);
  u = (u + 0x7FFFu + ((u >> 16) & 1u)) >> 16;
  return (ushort_t)u;
}

// in: [32][RR] f32  ->  out: [RR][32] bf16   (3 planes per launch)
__global__ __launch_bounds__(256) void transpose3(TP3 tp) {
  const float* __restrict__ in = tp.src[blockIdx.y];
  ushort_t* __restrict__ out = tp.dst[blockIdx.y];
  const int RR = tp.RR;
  __shared__ float tile[32][65];
  const int p0 = blockIdx.x * 64;
  {
    const int tp_ = threadIdx.x & 63;
    const int tc = threadIdx.x >> 6;
#pragma unroll
    for (int cc = 0; cc < 8; ++cc) {
      const int c = cc * 4 + tc;
      tile[c][tp_] = in[(size_t)c * RR + p0 + tp_];
    }
  }
  __syncthreads();
  {
    const int c2 = threadIdx.x & 15;
    const int tq = threadIdx.x >> 4;
    uint_t* o32 = (uint_t*)out;
#pragma unroll
    for (int pp = 0; pp < 4; ++pp) {
      const int pos = pp * 16 + tq;
      const uint_t lo = f32_to_bf16_rne(tile[2 * c2 + 0][pos]);
      const uint_t hi = f32_to_bf16_rne(tile[2 * c2 + 1][pos]);
      o32[(size_t)(p0 + pos) * 16 + c2] = lo | (hi << 16);
    }
  }
}

// w0 [128][64] -> w0T [64][128] bf16 ; w1 [64][64] -> w1T [64][64] bf16
__global__ __launch_bounds__(256) void prep_weights(
    const float* __restrict__ w0, const float* __restrict__ w1,
    ushort_t* __restrict__ w0T, ushort_t* __restrict__ w1T) {
  const int t = threadIdx.x;
  for (int i = t; i < 128 * 64; i += 256) {
    const int k = i >> 6, n = i & 63;
    w0T[n * 128 + k] = f32_to_bf16_rne(w0[i]);
  }
  for (int i = t; i < 64 * 64; i += 256) {
    const int k = i >> 6, n = i & 63;
    w1T[n * 64 + k] = f32_to_bf16_rne(w1[i]);
  }
}

// ---------------- Morton counting sort ------------------------------------
__device__ __forceinline__ uint_t spread5(uint_t v) {
  return (v & 1u) | ((v & 2u) << 2) | ((v & 4u) << 4) | ((v & 8u) << 6) |
         ((v & 16u) << 8);
}
__device__ __forceinline__ uint_t morton_key(const float* __restrict__ x,
                                             int i) {
  const float a = x[3 * i + 0];
  const float b = x[3 * i + 1];
  const float c = x[3 * i + 2];
  const uint_t ua = (uint_t)fminf(fmaxf((a + 1.0f) * 16.0f, 0.0f), 31.0f);
  const uint_t ub = (uint_t)fminf(fmaxf((b + 1.0f) * 16.0f, 0.0f), 31.0f);
  const uint_t uc = (uint_t)fminf(fmaxf((c + 1.0f) * 16.0f, 0.0f), 31.0f);
  return spread5(ua) | (spread5(ub) << 1) | (spread5(uc) << 2);
}

__global__ __launch_bounds__(256) void sort_hist(const float* __restrict__ x,
                                                 uint_t* __restrict__ cnt,
                                                 int N) {
  const int i = blockIdx.x * 256 + threadIdx.x;
  if (i < N) atomicAdd(&cnt[morton_key(x, i)], 1u);
}

__global__ __launch_bounds__(1024) void sort_scan(uint_t* __restrict__ cnt) {
  __shared__ uint_t s[1024];
  const int t = threadIdx.x;
  const int base = t * 32;
  uint_t p = 0;
#pragma unroll
  for (int e = 0; e < 32; ++e) p += cnt[base + e];
  s[t] = p;
  __syncthreads();
  for (int off = 1; off < 1024; off <<= 1) {
    uint_t v = 0;
    if (t >= off) v = s[t - off];
    __syncthreads();
    s[t] += v;
    __syncthreads();
  }
  uint_t running = s[t] - p;  // exclusive prefix of this chunk
#pragma unroll
  for (int e = 0; e < 32; ++e) {
    const uint_t old = cnt[base + e];
    cnt[base + e] = running;
    running += old;
  }
}

__global__ __launch_bounds__(256) void sort_scatter(
    const float* __restrict__ x, uint_t* __restrict__ cnt,
    int* __restrict__ sidx, float* __restrict__ xs, int N) {
  const int i = blockIdx.x * 256 + threadIdx.x;
  if (i >= N) return;
  const uint_t key = morton_key(x, i);
  const uint_t pos = atomicAdd(&cnt[key], 1u);
  sidx[pos] = i;
  xs[3 * pos + 0] = x[3 * i + 0];
  xs[3 * pos + 1] = x[3 * i + 1];
  xs[3 * pos + 2] = x[3 * i + 2];
}

// ---------------- fused sample + MFMA MLP ---------------------------------
template <bool SORTED>
__global__ __launch_bounds__(512, 8) void kplanes_fused_mfma(KParams P) {
  // Arena (exactly 40960 B -> 4 blocks/CU):
  //  [0,24576)  coords: 768 sets x 8 dwords {o00,o01,o10,o11,wx,wy,-,-}
  //             reused later: lds_h [0,8192), oparts [8192,8704)
  //  [24576,40960) lds_feat [64][64] dwords (bf16 pairs), XOR-swizzled
  //             reused earlier: px staging [24576,25344)
  __shared__ float arena[10240];
  int* ci = (int*)arena;
  float* cf = arena;
  uint_t* feat32 = (uint_t*)(arena + 6144);
  float* px = arena + 6144;

  const int t = threadIdx.x;

  // bijective XCD-chunked swizzle (consecutive sorted blocks share an XCD L2)
  int bid = blockIdx.x;
  if (SORTED) {
    const int nblk = gridDim.x;
    const int q = nblk >> 3, r = nblk & 7;
    const int xcd = bid & 7, idx = bid >> 3;
    bid = (xcd < r ? xcd * (q + 1) : r * (q + 1) + (xcd - r) * q) + idx;
  }
  const int blk0 = bid * 64;

  // ---------------- px staging: 64 pts x 3 coords -------------------------
  if (SORTED) {
    if (t < 192) {
      int idx = blk0 * 3 + t;
      if (idx >= 3 * P.N) idx = 3 * P.N - 3 + (t % 3);
      px[t] = P.xs[idx];
    }
  } else {
    if (t < 192) {
      const int p = t / 3, e = t - p * 3;
      int Pi = blk0 + p;
      if (Pi >= P.N) Pi = P.N - 1;
      px[t] = P.x[3 * Pi + e];
    }
  }
  __syncthreads();

  // ---------------- stage 1: coords once per (pt, sample) -----------------
  for (int task = t; task < 768; task += 512) {
    const int pt = task & 63;
    const int sm = task >> 6;
    const int pl = sm >> 2;
    const int s = sm & 3;
    const float cx = (pl == 2) ? px[pt * 3 + 1] : px[pt * 3 + 0];
    const float cy = (pl == 0) ? px[pt * 3 + 1] : px[pt * 3 + 2];
    const int R = 128 << s;
    const float Rm1 = (float)(R - 1);
    const float u = fminf(fmaxf((cx + 1.0f) * 0.5f * Rm1, 0.0f), Rm1);
    const float v = fminf(fmaxf((cy + 1.0f) * 0.5f * Rm1, 0.0f), Rm1);
    const float fx0 = floorf(u), fy0 = floorf(v);
    const int x0 = (int)fx0, y0 = (int)fy0;
    const int x1 = min(x0 + 1, R - 1), y1 = min(y0 + 1, R - 1);
    const int base = task * 8;
    int4 o4;
    o4.x = y0 * R + x0;
    o4.y = y0 * R + x1;
    o4.z = y1 * R + x0;
    o4.w = y1 * R + x1;
    *(int4*)(ci + base) = o4;
    cf[base + 4] = u - fx0;
    cf[base + 5] = v - fy0;
  }
  __syncthreads();

  // ---------------- stage 2: gather, 16B loads, planes in-register --------
  const int pt = t >> 3;
  const int q = t & 7;
  const int cg = q & 3;
  const int sh = q >> 2;
  uint_t* prow = feat32 + pt * 64;
  const int wxor = (pt & 7) << 2;

#pragma unroll
  for (int j = 0; j < 2; ++j) {
    const int s = 2 * j + sh;
    float f[8];
#pragma unroll
    for (int c = 0; c < 8; ++c) f[c] = 1.0f;

#pragma unroll
    for (int pl = 0; pl < 3; ++pl) {
      const int base = ((pl * 4 + s) * 64 + pt) * 8;
      const int4 o4 = *(const int4*)(ci + base);
      const float wx = cf[base + 4], wy = cf[base + 5];
      const float w11 = wx * wy;
      const float w10 = wy - w11;
      const float w01 = wx - w11;
      const float w00 = 1.0f - wx - w10;
      const ushort_t* gp = (const ushort_t*)P.g[s * 3 + pl];
      const uint4 qa = *(const uint4*)(gp + (size_t)o4.x * 32 + cg * 8);
      const uint4 qb = *(const uint4*)(gp + (size_t)o4.y * 32 + cg * 8);
      const uint4 qc = *(const uint4*)(gp + (size_t)o4.z * 32 + cg * 8);
      const uint4 qd = *(const uint4*)(gp + (size_t)o4.w * 32 + cg * 8);
#define CH2(dA, dB, dC, dD, i0, i1)                                \
  {                                                                \
    float rl = __uint_as_float((dD) << 16) * w11;                  \
    rl = fmaf(__uint_as_float((dC) << 16), w10, rl);               \
    rl = fmaf(__uint_as_float((dB) << 16), w01, rl);               \
    rl = fmaf(__uint_as_float((dA) << 16), w00, rl);               \
    f[i0] *= rl;                                                   \
    float rh = __uint_as_float((dD)&0xFFFF0000u) * w11;            \
    rh = fmaf(__uint_as_float((dC)&0xFFFF0000u), w10, rh);         \
    rh = fmaf(__uint_as_float((dB)&0xFFFF0000u), w01, rh);         \
    rh = fmaf(__uint_as_float((dA)&0xFFFF0000u), w00, rh);         \
    f[i1] *= rh;                                                   \
  }
      CH2(qa.x, qb.x, qc.x, qd.x, 0, 1)
      CH2(qa.y, qb.y, qc.y, qd.y, 2, 3)
      CH2(qa.z, qb.z, qc.z, qd.z, 4, 5)
      CH2(qa.w, qb.w, qc.w, qd.w, 6, 7)
#undef CH2
    }

    uint_t d0, d1, d2, d3;
    asm("v_cvt_pk_bf16_f32 %0, %1, %2" : "=v"(d0) : "v"(f[0]), "v"(f[1]));
    asm("v_cvt_pk_bf16_f32 %0, %1, %2" : "=v"(d1) : "v"(f[2]), "v"(f[3]));
    asm("v_cvt_pk_bf16_f32 %0, %1, %2" : "=v"(d2) : "v"(f[4]), "v"(f[5]));
    asm("v_cvt_pk_bf16_f32 %0, %1, %2" : "=v"(d3) : "v"(f[6]), "v"(f[7]));
    uint4 dv;
    dv.x = d0; dv.y = d1; dv.z = d2; dv.w = d3;
    *(uint4*)(prow + ((s * 16 + cg * 4) ^ wxor)) = dv;
  }
  __syncthreads();

  // ---------------- MLP via MFMA (HW-validated frag maps) -----------------
  ushort_t* lds_h = (ushort_t*)arena;
  float(*oparts)[64] = (float(*)[64])(arena + 2048);

  const int w = __builtin_amdgcn_readfirstlane(t >> 6);
  const int mt = w & 3;
  const int nt0 = (w >> 2) << 1;
  const int ln = t & 15;
  const int lq = (t >> 4) & 3;
  const int arow = mt * 16 + ln;

  const uint_t* farow = feat32 + arow * 64;
  const int axor = (arow & 7) << 2;
  f32x4 acc0a = {0.f, 0.f, 0.f, 0.f}, acc0b = {0.f, 0.f, 0.f, 0.f};
  const ushort_t* w0a = P.w0T + (nt0 * 16 + ln) * 128 + lq * 8;
  const ushort_t* w0b = w0a + 16 * 128;
#pragma unroll
  for (int kt = 0; kt < 4; ++kt) {
    const bf16x8 aF = *(const bf16x8*)(farow + ((kt * 16 + lq * 4) ^ axor));
    const bf16x8 bFa = *(const bf16x8*)(w0a + kt * 32);
    const bf16x8 bFb = *(const bf16x8*)(w0b + kt * 32);
    acc0a = __builtin_amdgcn_mfma_f32_16x16x32_bf16(aF, bFa, acc0a, 0, 0, 0);
    acc0b = __builtin_amdgcn_mfma_f32_16x16x32_bf16(aF, bFb, acc0b, 0, 0, 0);
  }

#pragma unroll
  for (int i = 0; i < 2; ++i) {
    const f32x4 a = i ? acc0b : acc0a;
    const int col = (nt0 + i) * 16 + ln;
#pragma unroll
    for (int jj = 0; jj < 4; ++jj) {
      const float v = fmaxf(a[jj], 0.0f);
      uint_t dv;
      asm("v_cvt_pk_bf16_f32 %0, %1, %2" : "=v"(dv) : "v"(v), "v"(v));
      const int r = mt * 16 + lq * 4 + jj;
      lds_h[r * 64 + (col ^ ((r & 7) << 3))] = (ushort_t)dv;
    }
  }
  __syncthreads();

  const ushort_t* hrow = lds_h + arow * 64;
  const int hxor = (arow & 7) << 3;
  f32x4 acc1a = {0.f, 0.f, 0.f, 0.f}, acc1b = {0.f, 0.f, 0.f, 0.f};
  const ushort_t* w1a = P.w1T + (nt0 * 16 + ln) * 64 + lq * 8;
  const ushort_t* w1b = w1a + 16 * 64;
#pragma unroll
  for (int kt = 0; kt < 2; ++kt) {
    const bf16x8 aF = *(const bf16x8*)(hrow + ((kt * 32 + lq * 8) ^ hxor));
    const bf16x8 bFa = *(const bf16x8*)(w1a + kt * 32);
    const bf16x8 bFb = *(const bf16x8*)(w1b + kt * 32);
    acc1a = __builtin_amdgcn_mfma_f32_16x16x32_bf16(aF, bFa, acc1a, 0, 0, 0);
    acc1b = __builtin_amdgcn_mfma_f32_16x16x32_bf16(aF, bFb, acc1b, 0, 0, 0);
  }

  const float w2a = P.w2[nt0 * 16 + ln];
  const float w2b = P.w2[(nt0 + 1) * 16 + ln];
  float part[4];
#pragma unroll
  for (int jj = 0; jj < 4; ++jj)
    part[jj] = fmaxf(acc1a[jj], 0.f) * w2a + fmaxf(acc1b[jj], 0.f) * w2b;
#pragma unroll
  for (int jj = 0; jj < 4; ++jj) {
    part[jj] += __shfl_xor(part[jj], 1);
    part[jj] += __shfl_xor(part[jj], 2);
    part[jj] += __shfl_xor(part[jj], 4);
    part[jj] += __shfl_xor(part[jj], 8);
  }
  if (ln == 0) {
#pragma unroll
    for (int jj = 0; jj < 4; ++jj)
      oparts[w >> 2][mt * 16 + lq * 4 + jj] = part[jj];
  }
  __syncthreads();

  if (t < 64) {
    const int Po = blk0 + t;
    if (Po < P.N) {
      const float r = oparts[0][t] + oparts[1][t];
      if (SORTED)
        P.out[P.sidx[Po]] = r;
      else
        P.out[Po] = r;
    }
  }
}

// fallback (ws too small): f32 [C,H,W] grids, scalar MLP (R3 structure)
__global__ __launch_bounds__(512, 8) void kplanes_fused_scalar(KParams P) {
  __shared__ float fl[64][130];
  const int t = threadIdx.x;
  const int pg = t >> 3;
  const int sub = t & 7;
  const int blk0 = blockIdx.x * 64;

  int Pi = blk0 + pg;
  if (Pi >= P.N) Pi = P.N - 1;
  const float c0 = P.x[3 * Pi + 0];
  const float c1 = P.x[3 * Pi + 1];
  const float c2 = P.x[3 * Pi + 2];

  float feat[4][4];
#pragma unroll
  for (int s = 0; s < 4; ++s)
#pragma unroll
    for (int c = 0; c < 4; ++c) feat[s][c] = 1.0f;

#pragma unroll
  for (int s = 0; s < 4; ++s) {
    const int R = 128 << s;
    const int RR = R * R;
#pragma unroll
    for (int pl = 0; pl < 3; ++pl) {
      const float cx = (pl == 2) ? c1 : c0;
      const float cy = (pl == 0) ? c1 : c2;
      const float Rm1 = (float)(R - 1);
      const float u = fminf(fmaxf((cx + 1.0f) * 0.5f * Rm1, 0.0f), Rm1);
      const float v = fminf(fmaxf((cy + 1.0f) * 0.5f * Rm1, 0.0f), Rm1);
      const float fx0 = floorf(u), fy0 = floorf(v);
      const float wx = u - fx0, wy = v - fy0;
      const int x0 = (int)fx0, y0 = (int)fy0;
      const int x1 = min(x0 + 1, R - 1), y1 = min(y0 + 1, R - 1);
      const float w11 = wx * wy;
      const float w10 = wy - w11;
      const float w01 = wx - w11;
      const float w00 = 1.0f - wx - w10;
      const float* gp = (const float*)P.g[s * 3 + pl];
      const int i00 = y0 * R + x0, i01 = y0 * R + x1;
      const int i10 = y1 * R + x0, i11 = y1 * R + x1;
#pragma unroll
      for (int c = 0; c < 4; ++c) {
        const size_t cb = (size_t)(sub * 4 + c) * RR;
        feat[s][c] *= gp[cb + i00] * w00 + gp[cb + i01] * w01 +
                      gp[cb + i10] * w10 + gp[cb + i11] * w11;
      }
    }
  }

#pragma unroll
  for (int s = 0; s < 4; ++s)
#pragma unroll
    for (int c = 0; c < 4; ++c)
      fl[pg][s * 32 + sub * 4 + c] = feat[s][c];
  __syncthreads();

  const int p = t & 63;
  const int g = __builtin_amdgcn_readfirstlane(t >> 6);

  const float* w0c = P.w0 + g * 8;
  float part[8];
#pragma unroll
  for (int jj = 0; jj < 8; ++jj) part[jj] = 0.0f;
#pragma unroll 16
  for (int k = 0; k < 128; ++k) {
    const float f = fl[p][k];
#pragma unroll
    for (int jj = 0; jj < 8; ++jj)
      part[jj] = fmaf(f, w0c[(size_t)k * 64 + jj], part[jj]);
  }
  __syncthreads();
#pragma unroll
  for (int jj = 0; jj < 8; ++jj)
    fl[p][g * 8 + jj] = fmaxf(part[jj], 0.0f);
  __syncthreads();

  const float* w1c = P.w1 + g * 8;
  float h1[8];
#pragma unroll
  for (int jj = 0; jj < 8; ++jj) h1[jj] = 0.0f;
#pragma unroll 16
  for (int k = 0; k < 64; ++k) {
    const float a = fl[p][k];
#pragma unroll
    for (int jj = 0; jj < 8; ++jj)
      h1[jj] = fmaf(a, w1c[(size_t)k * 64 + jj], h1[jj]);
  }

  const float* w2c = P.w2 + g * 8;
  float o = 0.0f;
#pragma unroll
  for (int jj = 0; jj < 8; ++jj)
    o = fmaf(fmaxf(h1[jj], 0.0f), w2c[jj], o);

  __syncthreads();
  ((float*)fl)[g * 64 + p] = o;
  __syncthreads();

  if (t < 64) {
    const int Po = blk0 + t;
    if (Po < P.N) {
      const float* f0 = (const float*)fl;
      float r = 0.0f;
#pragma unroll
      for (int j = 0; j < 8; ++j) r += f0[j * 64 + t];
      P.out[Po] = r;
    }
  }
}

extern "C" void kernel_launch(void* const* d_in, const int* in_sizes, int n_in,
                              void* d_out, int out_size, void* d_ws, size_t ws_size,
                              hipStream_t stream) {
  KParams P;
  P.x = (const float*)d_in[0];
  P.w0 = (const float*)d_in[13];
  P.w1 = (const float*)d_in[14];
  P.w2 = (const float*)d_in[15];
  P.out = (float*)d_out;
  const int N = in_sizes[0] / 3;
  P.N = N;
  P.xs = nullptr;
  P.sidx = nullptr;

  size_t need = 0;
  for (int s = 0; s < 4; ++s) {
    const size_t R = (size_t)(128 << s);
    need += 3ull * 32ull * R * R * sizeof(ushort_t);
  }
  const size_t walign = (need + 255) & ~(size_t)255;
  const size_t wbytes = (size_t)(64 * 128 + 64 * 64) * sizeof(ushort_t);
  const size_t cntoff = (walign + wbytes + 255) & ~(size_t)255;
  const size_t cntbytes = (size_t)NBUCKET * 4;
  const size_t sidxoff = cntoff + cntbytes;
  const size_t xsoff = (sidxoff + (size_t)N * 4 + 255) & ~(size_t)255;
  const size_t total_sorted = xsoff + (size_t)N * 12;

  const int nblk = (N + 63) / 64;
  if (ws_size >= walign + wbytes) {
    ushort_t* w = (ushort_t*)d_ws;
    size_t off = 0;
    for (int s = 0; s < 4; ++s) {
      const int R = 128 << s;
      const int RR = R * R;
      TP3 tp;
      tp.RR = RR;
      for (int pl = 0; pl < 3; ++pl) {
        tp.src[pl] = (const float*)d_in[1 + s * 3 + pl];
        tp.dst[pl] = w + off;
        P.g[s * 3 + pl] = w + off;
        off += (size_t)32 * RR;
      }
      dim3 grid(RR / 64, 3);
      transpose3<<<grid, 256, 0, stream>>>(tp);
    }
    ushort_t* w0T = (ushort_t*)((char*)d_ws + walign);
    ushort_t* w1T = w0T + 64 * 128;
    P.w0T = w0T;
    P.w1T = w1T;
    prep_weights<<<1, 256, 0, stream>>>(P.w0, P.w1, w0T, w1T);

    if (ws_size >= total_sorted) {
      uint_t* cnt = (uint_t*)((char*)d_ws + cntoff);
      int* sidx = (int*)((char*)d_ws + sidxoff);
      float* xs = (float*)((char*)d_ws + xsoff);
      hipMemsetAsync(cnt, 0, cntbytes, stream);
      const int pblk = (N + 255) / 256;
      sort_hist<<<pblk, 256, 0, stream>>>(P.x, cnt, N);
      sort_scan<<<1, 1024, 0, stream>>>(cnt);
      sort_scatter<<<pblk, 256, 0, stream>>>(P.x, cnt, sidx, xs, N);
      P.xs = xs;
      P.sidx = sidx;
      kplanes_fused_mfma<true><<<nblk, 512, 0, stream>>>(P);
    } else {
      kplanes_fused_mfma<false><<<nblk, 512, 0, stream>>>(P);
    }
  } else {
    for (int k = 0; k < 12; ++k) P.g[k] = (const void*)d_in[1 + k];
    P.w0T = nullptr;
    P.w1T = nullptr;
    kplanes_fused_scalar<<<nblk, 512, 0, stream>>>(P);
  }
}